// Round 8
// baseline (247.810 us; speedup 1.0000x reference)
//
#include <hip/hip_runtime.h>
#include <stdint.h>
#include <stddef.h>

// Problem constants
#define SEQ   2048
#define DIM   1024
#define NH    16
#define HD    64
#define MTOT  4096   // B*S
#define LPAD  72     // LDS row stride (shorts): 144B = +4 banks/row -> optimal 8-lanes/bank reads
#define EPAD  136    // epilogue bf16 tile stride (shorts): 272B, 16B-aligned rows, +4 banks/row
#define FPAD  132    // epilogue fp32 slab stride (floats): 528B, 16B-aligned rows, +4 banks/row

typedef __attribute__((ext_vector_type(8))) short short8;         // 8 bf16 = 4 VGPRs
typedef __attribute__((ext_vector_type(4))) float floatx4;        // MFMA C/D
typedef __attribute__((ext_vector_type(4))) float float4v;
typedef __attribute__((ext_vector_type(4))) unsigned short ushort4v;

__device__ __forceinline__ floatx4 mfma_bf16(short8 a, short8 b, floatx4 c) {
    return __builtin_amdgcn_mfma_f32_16x16x32_bf16(a, b, c, 0, 0, 0);
}

__device__ __forceinline__ float b2f(unsigned short s) {
    unsigned int u = ((unsigned int)s) << 16;
    return __builtin_bit_cast(float, u);
}
__device__ __forceinline__ unsigned short f2b(float f) {  // RNE
    unsigned int u = __builtin_bit_cast(unsigned int, f);
    u += 0x7fffu + ((u >> 16) & 1u);
    return (unsigned short)(u >> 16);
}

// ---------------- fp32 -> bf16 bulk convert (X) ----------------
__global__ __launch_bounds__(256) void cvt_f32_bf16(const float* __restrict__ in,
                                                    unsigned short* __restrict__ out) {
    const int i = (blockIdx.x * 256 + threadIdx.x) * 4;
    const float4v v = *(const float4v*)&in[i];
    ushort4v o;
    o.x = f2b(v.x); o.y = f2b(v.y); o.z = f2b(v.z); o.w = f2b(v.w);
    *(ushort4v*)&out[i] = o;
}

// ---------------- weight transpose+convert: W[K][N] f32 -> WT[N][K] bf16 ----------------
__global__ __launch_bounds__(256) void transpose_all(const float* __restrict__ w0,
                                                     const float* __restrict__ w1,
                                                     const float* __restrict__ w2,
                                                     const float* __restrict__ w3,
                                                     unsigned short* __restrict__ outbase) {
    __shared__ float t[64][65];
    const int z = blockIdx.z;
    const float* in = (z == 0) ? w0 : (z == 1) ? w1 : (z == 2) ? w2 : w3;
    unsigned short* out = outbase + (size_t)z * DIM * DIM;
    const int c0 = blockIdx.x * 64, r0 = blockIdx.y * 64;
    const int x = threadIdx.x, y = threadIdx.y;  // (64,4)
#pragma unroll
    for (int i = 0; i < 64; i += 4)
        t[y + i][x] = in[(size_t)(r0 + y + i) * DIM + c0 + x];
    __syncthreads();
#pragma unroll
    for (int i = 0; i < 64; i += 4)
        out[(size_t)(c0 + y + i) * DIM + r0 + x] = f2b(t[x][y + i]);
}

// ---------------- GEMM: C[m][n] = sum_k A[m][k]*BT[n][k] + bias[n] ----------------
// 128x128 tile, 4 waves (2x2 of 64x64), BK=64, pipelined staging.
// Vectorized LDS-staged epilogues (16B/lane coalesced stores).
__global__ __launch_bounds__(256) void gemm_fused(const unsigned short* __restrict__ A,
                                                  const unsigned short* __restrict__ WTbase,
                                                  const float* __restrict__ b0,
                                                  const float* __restrict__ b1,
                                                  const float* __restrict__ b2,
                                                  void* __restrict__ outbase,
                                                  int qkv) {
    __shared__ __attribute__((aligned(16))) unsigned short smem[2 * 128 * LPAD];  // 36864 B
    unsigned short* As = smem;
    unsigned short* Bs = smem + 128 * LPAD;

    const int z = blockIdx.z;
    const unsigned short* BT = WTbase + (size_t)z * (DIM * DIM);
    const float* bias        = (z == 0) ? b0 : (z == 1) ? b1 : b2;
    const int mode = qkv ? ((z == 2) ? 2 : 1) : 0;
    float* Cf          = (float*)outbase;
    unsigned short* Cb = (unsigned short*)outbase + (size_t)z * ((size_t)MTOT * DIM);

    const int tid = threadIdx.x;
    const int w = tid >> 6, lane = tid & 63;
    const int quad = lane >> 4, l16 = lane & 15;
    const int wm = w >> 1, wn = w & 1;
    const int m0 = blockIdx.y * 128, n0 = blockIdx.x * 128;
    const int bb = m0 >> 11;

    floatx4 acc[4][4];
#pragma unroll
    for (int mi = 0; mi < 4; ++mi)
#pragma unroll
        for (int ni = 0; ni < 4; ++ni) acc[mi][ni] = (floatx4)0.0f;

    const int srow = tid >> 3, scol = (tid & 7) * 8;  // staging: 8 threads/row

    short8 pa[4], pb[4];
#pragma unroll
    for (int ch = 0; ch < 4; ++ch) {
        pa[ch] = *(const short8*)&A[(size_t)(m0 + ch * 32 + srow) * DIM + scol];
        pb[ch] = *(const short8*)&BT[(size_t)(n0 + ch * 32 + srow) * DIM + scol];
    }

    for (int k0 = 0;; k0 += 64) {
#pragma unroll
        for (int ch = 0; ch < 4; ++ch) {
            *(short8*)&As[(ch * 32 + srow) * LPAD + scol] = pa[ch];
            *(short8*)&Bs[(ch * 32 + srow) * LPAD + scol] = pb[ch];
        }
        __syncthreads();  // tile visible
        const bool more = (k0 + 64 < DIM);
        if (more) {  // prefetch AFTER barrier; overlapped by MFMA phase below
#pragma unroll
            for (int ch = 0; ch < 4; ++ch) {
                pa[ch] = *(const short8*)&A[(size_t)(m0 + ch * 32 + srow) * DIM + k0 + 64 + scol];
                pb[ch] = *(const short8*)&BT[(size_t)(n0 + ch * 32 + srow) * DIM + k0 + 64 + scol];
            }
        }
#pragma unroll
        for (int kk = 0; kk < 2; ++kk) {
            short8 a[4], b[4];
#pragma unroll
            for (int mi = 0; mi < 4; ++mi)
                a[mi] = *(const short8*)&As[(wm * 64 + mi * 16 + l16) * LPAD + kk * 32 + quad * 8];
#pragma unroll
            for (int ni = 0; ni < 4; ++ni)
                b[ni] = *(const short8*)&Bs[(wn * 64 + ni * 16 + l16) * LPAD + kk * 32 + quad * 8];
#pragma unroll
            for (int mi = 0; mi < 4; ++mi)
#pragma unroll
                for (int ni = 0; ni < 4; ++ni)
                    acc[mi][ni] = mfma_bf16(a[mi], b[ni], acc[mi][ni]);
        }
        if (!more) break;
        __syncthreads();  // all waves done reading before next write
    }

    float bvv[4];
#pragma unroll
    for (int ni = 0; ni < 4; ++ni) bvv[ni] = bias[n0 + wn * 64 + ni * 16 + l16];

    if (mode == 0) {
        // fp32 row-major out, 4 passes of 32 m-rows x 128 n staged in LDS
        float* T = (float*)smem;  // 32 x FPAD floats
        for (int p = 0; p < 4; ++p) {
            __syncthreads();
            if (wm == (p >> 1)) {
                const int mib = (p & 1) * 2;
#pragma unroll
                for (int mm = 0; mm < 2; ++mm)
#pragma unroll
                    for (int ni = 0; ni < 4; ++ni)
#pragma unroll
                        for (int r = 0; r < 4; ++r)
                            T[(mm * 16 + quad * 4 + r) * FPAD + wn * 64 + ni * 16 + l16] =
                                acc[mib + mm][ni][r] + bvv[ni];
            }
            __syncthreads();
#pragma unroll
            for (int it = 0; it < 4; ++it) {
                const int c = it * 256 + tid;
                const int row = c >> 5, nof = (c & 31) * 4;
                *(float4v*)&Cf[(size_t)(m0 + p * 32 + row) * DIM + n0 + nof] =
                    *(const float4v*)&T[row * FPAD + nof];
            }
        }
    } else if (mode == 1) {
        // [B,H,S,Hd] bf16
        unsigned short* T = smem;  // 128 x EPAD shorts
        __syncthreads();
#pragma unroll
        for (int mi = 0; mi < 4; ++mi)
#pragma unroll
            for (int ni = 0; ni < 4; ++ni)
#pragma unroll
                for (int r = 0; r < 4; ++r)
                    T[(wm * 64 + mi * 16 + quad * 4 + r) * EPAD + wn * 64 + ni * 16 + l16] =
                        f2b(acc[mi][ni][r] + bvv[ni]);
        __syncthreads();
#pragma unroll
        for (int it = 0; it < 8; ++it) {
            const int c = it * 256 + tid;
            const int seg = c >> 3, d8 = (c & 7) * 8;
            const int mm = seg >> 1, hseg = seg & 1;
            const int h = (n0 >> 6) + hseg;
            const int s = (m0 & (SEQ - 1)) + mm;
            *(short8*)&Cb[((size_t)(bb * NH + h) * SEQ + s) * HD + d8] =
                *(const short8*)&T[mm * EPAD + hseg * 64 + d8];
        }
    } else {
        // [B,H,Hd,S] bf16 (V^T): stage transposed [n][m]
        unsigned short* T = smem;
        __syncthreads();
#pragma unroll
        for (int mi = 0; mi < 4; ++mi)
#pragma unroll
            for (int ni = 0; ni < 4; ++ni) {
                ushort4v pk;
#pragma unroll
                for (int r = 0; r < 4; ++r) pk[r] = f2b(acc[mi][ni][r] + bvv[ni]);
                *(ushort4v*)&T[(wn * 64 + ni * 16 + l16) * EPAD + wm * 64 + mi * 16 + quad * 4] = pk;
            }
        __syncthreads();
#pragma unroll
        for (int it = 0; it < 8; ++it) {
            const int c = it * 256 + tid;
            const int nrow = c >> 4, s8 = (c & 15) * 8;
            const int h = (n0 >> 6) + (nrow >> 6), d = nrow & 63;
            *(short8*)&Cb[((size_t)(bb * NH + h) * HD + d) * SEQ + (m0 & (SEQ - 1)) + s8] =
                *(const short8*)&T[nrow * EPAD + s8];
        }
    }
}

// ---------------- causal flash attention, key-split G=2 ----------------
// Flat softmax => attention is LINEAR over key chunks: block z handles
// j-tiles with j % 2 == z, writing UNNORMALIZED partial O (bf16) + partial l.
// grid (16 qtiles, 32 bh, 2), qt reversed (heavy first). block 256 = 4 waves,
// wave w owns 32 queries. Double-buffered K/V, one barrier/tile, prefetch
// after barrier. Q,K: [B,H,S,Hd]; VT: [B,H,Hd,S]; partial O: [B,S,H*Hd] bf16.
__global__ __launch_bounds__(256) void attn_fwd(const unsigned short* __restrict__ Q,
                                                const unsigned short* __restrict__ K,
                                                const unsigned short* __restrict__ VT,
                                                unsigned short* __restrict__ Op0,
                                                unsigned short* __restrict__ Op1,
                                                float* __restrict__ lbase) {
    __shared__ __attribute__((aligned(16))) unsigned short Ks[2][64 * LPAD];
    __shared__ __attribute__((aligned(16))) unsigned short Vs[2][64 * LPAD];
    __shared__ __attribute__((aligned(16))) unsigned short Ps[4][16 * LPAD];

    const int qt = (gridDim.x - 1) - blockIdx.x;
    const int bh = blockIdx.y;
    const int g  = blockIdx.z;
    unsigned short* Op = g ? Op1 : Op0;
    float* lp = lbase + (size_t)g * NH * 2 * SEQ + (size_t)bh * SEQ;

    const int tid = threadIdx.x;
    const int w = tid >> 6, lane = tid & 63;
    const int quad = lane >> 4, l16 = lane & 15;

    const unsigned short* Qh = Q  + (size_t)bh * SEQ * HD;
    const unsigned short* Kh = K  + (size_t)bh * SEQ * HD;
    const unsigned short* Vh = VT + (size_t)bh * HD * SEQ;
    const int q0 = qt * 128 + w * 32;
    const int jmax = 2 * qt + 1;

    // Q fragments pre-scaled by Hd^-0.5 = 0.125 (exact pow2 mul in bf16)
    short8 qf[2][2];
#pragma unroll
    for (int mi = 0; mi < 2; ++mi)
#pragma unroll
        for (int kk = 0; kk < 2; ++kk) {
            short8 t = *(const short8*)(Qh + (size_t)(q0 + mi * 16 + l16) * HD + kk * 32 + quad * 8);
            short8 o;
#pragma unroll
            for (int e = 0; e < 8; ++e)
                o[e] = (short)f2b(b2f((unsigned short)t[e]) * 0.125f);
            qf[mi][kk] = o;
        }

    floatx4 o_acc[2][4];
#pragma unroll
    for (int mi = 0; mi < 2; ++mi)
#pragma unroll
        for (int ni = 0; ni < 4; ++ni) o_acc[mi][ni] = (floatx4)0.0f;
    float l_i[2][4];
#pragma unroll
    for (int mi = 0; mi < 2; ++mi)
#pragma unroll
        for (int r = 0; r < 4; ++r) l_i[mi][r] = 0.0f;

    const int srow = tid >> 3, scol = (tid & 7) * 8;

    // prologue: prefetch tile j=g
    short8 kp0 = *(const short8*)&Kh[(size_t)(g * 64 + srow) * HD + scol];
    short8 kp1 = *(const short8*)&Kh[(size_t)(g * 64 + srow + 32) * HD + scol];
    short8 vp0 = *(const short8*)&Vh[(size_t)srow * SEQ + g * 64 + scol];
    short8 vp1 = *(const short8*)&Vh[(size_t)(srow + 32) * SEQ + g * 64 + scol];

    int buf = 0;
    for (int j = g; j <= jmax; j += 2, buf ^= 1) {
        *(short8*)&Ks[buf][srow * LPAD + scol]        = kp0;
        *(short8*)&Ks[buf][(srow + 32) * LPAD + scol] = kp1;
        *(short8*)&Vs[buf][srow * LPAD + scol]        = vp0;
        *(short8*)&Vs[buf][(srow + 32) * LPAD + scol] = vp1;
        __syncthreads();  // single barrier/iter (2-iteration buffer separation)
        if (j + 2 <= jmax) {  // prefetch AFTER barrier -> in flight across compute
            kp0 = *(const short8*)&Kh[(size_t)((j + 2) * 64 + srow) * HD + scol];
            kp1 = *(const short8*)&Kh[(size_t)((j + 2) * 64 + srow + 32) * HD + scol];
            vp0 = *(const short8*)&Vh[(size_t)srow * SEQ + (j + 2) * 64 + scol];
            vp1 = *(const short8*)&Vh[(size_t)(srow + 32) * SEQ + (j + 2) * 64 + scol];
        }

        if (j * 64 <= q0 + 31) {  // wave-uniform: skip fully-masked tiles
            floatx4 s_acc[2][4];
#pragma unroll
            for (int mi = 0; mi < 2; ++mi)
#pragma unroll
                for (int ni = 0; ni < 4; ++ni) s_acc[mi][ni] = (floatx4)0.0f;
#pragma unroll
            for (int kk = 0; kk < 2; ++kk)
#pragma unroll
                for (int ni = 0; ni < 4; ++ni) {
                    const short8 b = *(const short8*)&Ks[buf][(ni * 16 + l16) * LPAD + kk * 32 + quad * 8];
#pragma unroll
                    for (int mi = 0; mi < 2; ++mi)
                        s_acc[mi][ni] = mfma_bf16(qf[mi][kk], b, s_acc[mi][ni]);
                }

#pragma unroll
            for (int mi = 0; mi < 2; ++mi) {
                float p[4][4], rs[4];
#pragma unroll
                for (int r = 0; r < 4; ++r) {
                    const int q = q0 + mi * 16 + quad * 4 + r;
#pragma unroll
                    for (int ni = 0; ni < 4; ++ni) {
                        const int key = j * 64 + ni * 16 + l16;
                        p[ni][r] = (key > q) ? 0.0f : __expf(s_acc[mi][ni][r]);
                    }
                    rs[r] = (p[0][r] + p[1][r]) + (p[2][r] + p[3][r]);
                }
#pragma unroll
                for (int off = 1; off < 16; off <<= 1)
#pragma unroll
                    for (int r = 0; r < 4; ++r)
                        rs[r] += __shfl_xor(rs[r], off);
#pragma unroll
                for (int r = 0; r < 4; ++r) l_i[mi][r] += rs[r];

#pragma unroll
                for (int ni = 0; ni < 4; ++ni)
#pragma unroll
                    for (int r = 0; r < 4; ++r)
                        Ps[w][(quad * 4 + r) * LPAD + ni * 16 + l16] = f2b(p[ni][r]);

#pragma unroll
                for (int kk = 0; kk < 2; ++kk) {
                    const short8 pa = *(const short8*)&Ps[w][l16 * LPAD + kk * 32 + quad * 8];
#pragma unroll
                    for (int ni = 0; ni < 4; ++ni) {
                        const short8 vb = *(const short8*)&Vs[buf][(ni * 16 + l16) * LPAD + kk * 32 + quad * 8];
                        o_acc[mi][ni] = mfma_bf16(pa, vb, o_acc[mi][ni]);
                    }
                }
            }
        }
    }

    // partial-l store (all lanes hold the reduced sum; lane l16==0, quad-row mapping)
    if (l16 == 0) {
#pragma unroll
        for (int mi = 0; mi < 2; ++mi)
#pragma unroll
            for (int r = 0; r < 4; ++r)
                lp[q0 + mi * 16 + quad * 4 + r] = l_i[mi][r];
    }

    // partial-O epilogue: stage UNNORMALIZED [128 q][64 d] bf16, coalesced stores
    __syncthreads();
    unsigned short* T = (unsigned short*)Ks;  // 128 x LPAD shorts
#pragma unroll
    for (int mi = 0; mi < 2; ++mi)
#pragma unroll
        for (int ni = 0; ni < 4; ++ni)
#pragma unroll
            for (int r = 0; r < 4; ++r)
                T[(w * 32 + mi * 16 + quad * 4 + r) * LPAD + ni * 16 + l16] =
                    f2b(o_acc[mi][ni][r]);
    __syncthreads();
    const int bb = bh >> 4, h = bh & 15;
#pragma unroll
    for (int it = 0; it < 4; ++it) {
        const int c = it * 256 + tid;
        const int qrow = c >> 3, d8 = (c & 7) * 8;
        *(short8*)&Op[(size_t)(bb * SEQ + qt * 128 + qrow) * DIM + h * HD + d8] =
            *(const short8*)&T[qrow * LPAD + d8];
    }
}

// ---------------- combine partials: Ob = (p0 + p1) / (l0 + l1) ----------------
// In-place safe for Ob==p0 (each thread reads then writes its own elements).
__global__ __launch_bounds__(256) void attn_combine(const unsigned short* __restrict__ p0,
                                                    const unsigned short* __restrict__ p1,
                                                    const float* __restrict__ lbase,
                                                    unsigned short* __restrict__ Ob) {
    const size_t idx = ((size_t)blockIdx.x * 256 + threadIdx.x) * 8;
    const int row = (int)(idx >> 10);          // q-row in [0, 4096)
    const int col = (int)(idx & 1023);
    const int b = row >> 11, s = row & (SEQ - 1), h = col >> 6;
    const int bh = b * NH + h;
    const float l0 = lbase[(size_t)bh * SEQ + s];
    const float l1 = lbase[(size_t)NH * 2 * SEQ + (size_t)bh * SEQ + s];
    const float inv = 1.0f / (l0 + l1);
    const ushort4v a0 = *(const ushort4v*)&p0[idx];
    const ushort4v a1 = *(const ushort4v*)&p0[idx + 4];
    const ushort4v c0 = *(const ushort4v*)&p1[idx];
    const ushort4v c1 = *(const ushort4v*)&p1[idx + 4];
    ushort4v o0, o1;
#pragma unroll
    for (int e = 0; e < 4; ++e) {
        o0[e] = f2b((b2f(a0[e]) + b2f(c0[e])) * inv);
        o1[e] = f2b((b2f(a1[e]) + b2f(c1[e])) * inv);
    }
    *(ushort4v*)&Ob[idx]     = o0;
    *(ushort4v*)&Ob[idx + 4] = o1;
}

// ---------------- host launch ----------------
extern "C" void kernel_launch(void* const* d_in, const int* in_sizes, int n_in,
                              void* d_out, int out_size, void* d_ws, size_t ws_size,
                              hipStream_t stream) {
    // Reference dtypes are float32 — inputs and output are fp32.
    const float* X  = (const float*)d_in[0];
    const float* Wq = (const float*)d_in[1];
    const float* bq = (const float*)d_in[2];
    const float* Wk = (const float*)d_in[3];
    const float* bk = (const float*)d_in[4];
    const float* Wv = (const float*)d_in[5];
    const float* bv = (const float*)d_in[6];
    const float* Wo = (const float*)d_in[7];
    const float* bo = (const float*)d_in[8];

    unsigned short* ws = (unsigned short*)d_ws;
    const size_t WSZ = (size_t)DIM * DIM;    // 1M elems
    const size_t TSZ = (size_t)MTOT * DIM;   // 4M elems
    unsigned short* WqT = ws;                // 4 transposed weights (bf16), contiguous
    unsigned short* WoT = ws + 3 * WSZ;
    unsigned short* Qb  = ws + 4 * WSZ;      // Q,K,VT bf16, contiguous
    unsigned short* Kb  = Qb + TSZ;
    unsigned short* Vt  = Kb + TSZ;
    unsigned short* Ob  = Vt + TSZ;          // attn partial0 / combined out (bf16)
    // ws total: 4*2MB + 4*8MB = 40 MB

    // Dead-region reuse:
    //  - d_out[0:8MB): Xb (bf16 X) until QKV GEMM, then attn partial1
    //  - WqT[0:3*WSZ] (QKV weights): dead after QKV GEMM -> l partials (512 KB)
    unsigned short* Xb = (unsigned short*)d_out;
    unsigned short* Op1 = (unsigned short*)d_out;
    float* lb = (float*)ws;  // 2 * 32 * 2048 floats

    cvt_f32_bf16<<<dim3(TSZ / 1024), 256, 0, stream>>>(X, Xb);

    transpose_all<<<dim3(16, 16, 4), dim3(64, 4), 0, stream>>>(Wq, Wk, Wv, Wo, WqT);

    // fused QKV projections (z selects weight/bias/output+layout), bf16 out to ws
    gemm_fused<<<dim3(DIM / 128, MTOT / 128, 3), 256, 0, stream>>>(
        Xb, WqT, bq, bk, bv, (void*)Qb, 1);

    // key-split attention: partial0 -> Ob, partial1 -> d_out (Xb region, now dead)
    attn_fwd<<<dim3(SEQ / 128, 2 * NH, 2), 256, 0, stream>>>(Qb, Kb, Vt, Ob, Op1, lb);

    attn_combine<<<dim3((unsigned)(TSZ / (256 * 8))), 256, 0, stream>>>(Ob, Op1, lb, Ob);

    // output projection -> fp32 d_out
    gemm_fused<<<dim3(DIM / 128, MTOT / 128, 1), 256, 0, stream>>>(
        Ob, WoT, bo, bo, bo, d_out, 0);
}

// Round 9
// 226.022 us; speedup vs baseline: 1.0964x; 1.0964x over previous
//
#include <hip/hip_runtime.h>
#include <stdint.h>
#include <stddef.h>

// Problem constants
#define SEQ   2048
#define DIM   1024
#define NH    16
#define HD    64
#define MTOT  4096   // B*S
#define LPAD  72     // LDS row stride (shorts): 144B = +4 banks/row
#define EPAD  136    // epilogue bf16 tile stride (shorts)
#define FPAD  132    // epilogue fp32 slab stride (floats)

typedef __attribute__((ext_vector_type(8))) short short8;         // 8 bf16 = 4 VGPRs
typedef __attribute__((ext_vector_type(4))) float floatx4;        // MFMA C/D
typedef __attribute__((ext_vector_type(4))) float float4v;
typedef __attribute__((ext_vector_type(4))) unsigned short ushort4v;

__device__ __forceinline__ floatx4 mfma_bf16(short8 a, short8 b, floatx4 c) {
    return __builtin_amdgcn_mfma_f32_16x16x32_bf16(a, b, c, 0, 0, 0);
}

__device__ __forceinline__ float b2f(unsigned short s) {
    unsigned int u = ((unsigned int)s) << 16;
    return __builtin_bit_cast(float, u);
}
__device__ __forceinline__ unsigned short f2b(float f) {  // RNE
    unsigned int u = __builtin_bit_cast(unsigned int, f);
    u += 0x7fffu + ((u >> 16) & 1u);
    return (unsigned short)(u >> 16);
}

// ---------------- fp32 -> bf16 bulk convert (X) ----------------
__global__ __launch_bounds__(256) void cvt_f32_bf16(const float* __restrict__ in,
                                                    unsigned short* __restrict__ out) {
    const int i = (blockIdx.x * 256 + threadIdx.x) * 4;
    const float4v v = *(const float4v*)&in[i];
    ushort4v o;
    o.x = f2b(v.x); o.y = f2b(v.y); o.z = f2b(v.z); o.w = f2b(v.w);
    *(ushort4v*)&out[i] = o;
}

// ---------------- weight transpose+convert: W[K][N] f32 -> WT[N][K] bf16 ----------------
__global__ __launch_bounds__(256) void transpose_all(const float* __restrict__ w0,
                                                     const float* __restrict__ w1,
                                                     const float* __restrict__ w2,
                                                     const float* __restrict__ w3,
                                                     unsigned short* __restrict__ outbase) {
    __shared__ float t[64][65];
    const int z = blockIdx.z;
    const float* in = (z == 0) ? w0 : (z == 1) ? w1 : (z == 2) ? w2 : w3;
    unsigned short* out = outbase + (size_t)z * DIM * DIM;
    const int c0 = blockIdx.x * 64, r0 = blockIdx.y * 64;
    const int x = threadIdx.x, y = threadIdx.y;  // (64,4)
#pragma unroll
    for (int i = 0; i < 64; i += 4)
        t[y + i][x] = in[(size_t)(r0 + y + i) * DIM + c0 + x];
    __syncthreads();
#pragma unroll
    for (int i = 0; i < 64; i += 4)
        out[(size_t)(c0 + y + i) * DIM + r0 + x] = f2b(t[x][y + i]);
}

// ---------------- GEMM: C[m][n] = sum_k A[m][k]*BT[n][k] + bias[n] ----------------
// 128x128 tile, 4 waves (2x2 of 64x64), BK=64, pipelined staging.
// Output modes:
//   0: fp32 row-major [M][N]            (projection -> d_out)
//   1: bf16 [B,H,S,Hd]                  (Q)
//   3: bf16 KPACK: MFMA B-frag order    [bh][j][ni*2+kk][lane*8]  (K)
//   4: bf16 VPACK: MFMA B-frag order for PV (from V^T)            (V)
__global__ __launch_bounds__(256) void gemm_fused(const unsigned short* __restrict__ A,
                                                  const unsigned short* __restrict__ WTbase,
                                                  const float* __restrict__ b0,
                                                  const float* __restrict__ b1,
                                                  const float* __restrict__ b2,
                                                  void* __restrict__ outbase,
                                                  int qkv) {
    __shared__ __attribute__((aligned(16))) unsigned short smem[2 * 128 * LPAD];  // 36864 B
    unsigned short* As = smem;
    unsigned short* Bs = smem + 128 * LPAD;

    const int z = blockIdx.z;
    const unsigned short* BT = WTbase + (size_t)z * (DIM * DIM);
    const float* bias        = (z == 0) ? b0 : (z == 1) ? b1 : b2;
    const int mode = qkv ? ((z == 0) ? 1 : (z == 1) ? 3 : 4) : 0;
    float* Cf          = (float*)outbase;
    unsigned short* Cb = (unsigned short*)outbase + (size_t)z * ((size_t)MTOT * DIM);

    const int tid = threadIdx.x;
    const int w = tid >> 6, lane = tid & 63;
    const int quad = lane >> 4, l16 = lane & 15;
    const int wm = w >> 1, wn = w & 1;
    const int m0 = blockIdx.y * 128, n0 = blockIdx.x * 128;
    const int bb = m0 >> 11;

    floatx4 acc[4][4];
#pragma unroll
    for (int mi = 0; mi < 4; ++mi)
#pragma unroll
        for (int ni = 0; ni < 4; ++ni) acc[mi][ni] = (floatx4)0.0f;

    const int srow = tid >> 3, scol = (tid & 7) * 8;  // staging: 8 threads/row

    short8 pa[4], pb[4];
#pragma unroll
    for (int ch = 0; ch < 4; ++ch) {
        pa[ch] = *(const short8*)&A[(size_t)(m0 + ch * 32 + srow) * DIM + scol];
        pb[ch] = *(const short8*)&BT[(size_t)(n0 + ch * 32 + srow) * DIM + scol];
    }

    for (int k0 = 0;; k0 += 64) {
#pragma unroll
        for (int ch = 0; ch < 4; ++ch) {
            *(short8*)&As[(ch * 32 + srow) * LPAD + scol] = pa[ch];
            *(short8*)&Bs[(ch * 32 + srow) * LPAD + scol] = pb[ch];
        }
        __syncthreads();
        const bool more = (k0 + 64 < DIM);
        if (more) {
#pragma unroll
            for (int ch = 0; ch < 4; ++ch) {
                pa[ch] = *(const short8*)&A[(size_t)(m0 + ch * 32 + srow) * DIM + k0 + 64 + scol];
                pb[ch] = *(const short8*)&BT[(size_t)(n0 + ch * 32 + srow) * DIM + k0 + 64 + scol];
            }
        }
#pragma unroll
        for (int kk = 0; kk < 2; ++kk) {
            short8 a[4], b[4];
#pragma unroll
            for (int mi = 0; mi < 4; ++mi)
                a[mi] = *(const short8*)&As[(wm * 64 + mi * 16 + l16) * LPAD + kk * 32 + quad * 8];
#pragma unroll
            for (int ni = 0; ni < 4; ++ni)
                b[ni] = *(const short8*)&Bs[(wn * 64 + ni * 16 + l16) * LPAD + kk * 32 + quad * 8];
#pragma unroll
            for (int mi = 0; mi < 4; ++mi)
#pragma unroll
                for (int ni = 0; ni < 4; ++ni)
                    acc[mi][ni] = mfma_bf16(a[mi], b[ni], acc[mi][ni]);
        }
        if (!more) break;
        __syncthreads();
    }

    float bvv[4];
#pragma unroll
    for (int ni = 0; ni < 4; ++ni) bvv[ni] = bias[n0 + wn * 64 + ni * 16 + l16];

    if (mode == 0) {
        // fp32 row-major out, 4 passes of 32 m-rows x 128 n staged in LDS
        float* T = (float*)smem;
        for (int p = 0; p < 4; ++p) {
            __syncthreads();
            if (wm == (p >> 1)) {
                const int mib = (p & 1) * 2;
#pragma unroll
                for (int mm = 0; mm < 2; ++mm)
#pragma unroll
                    for (int ni = 0; ni < 4; ++ni)
#pragma unroll
                        for (int r = 0; r < 4; ++r)
                            T[(mm * 16 + quad * 4 + r) * FPAD + wn * 64 + ni * 16 + l16] =
                                acc[mib + mm][ni][r] + bvv[ni];
            }
            __syncthreads();
#pragma unroll
            for (int it = 0; it < 4; ++it) {
                const int c = it * 256 + tid;
                const int row = c >> 5, nof = (c & 31) * 4;
                *(float4v*)&Cf[(size_t)(m0 + p * 32 + row) * DIM + n0 + nof] =
                    *(const float4v*)&T[row * FPAD + nof];
            }
        }
    } else if (mode == 1) {
        // Q: [B,H,S,Hd] bf16
        unsigned short* T = smem;
        __syncthreads();
#pragma unroll
        for (int mi = 0; mi < 4; ++mi)
#pragma unroll
            for (int ni = 0; ni < 4; ++ni)
#pragma unroll
                for (int r = 0; r < 4; ++r)
                    T[(wm * 64 + mi * 16 + quad * 4 + r) * EPAD + wn * 64 + ni * 16 + l16] =
                        f2b(acc[mi][ni][r] + bvv[ni]);
        __syncthreads();
#pragma unroll
        for (int it = 0; it < 8; ++it) {
            const int c = it * 256 + tid;
            const int seg = c >> 3, d8 = (c & 7) * 8;
            const int mm = seg >> 1, hseg = seg & 1;
            const int h = (n0 >> 6) + hseg;
            const int s = (m0 & (SEQ - 1)) + mm;
            *(short8*)&Cb[((size_t)(bb * NH + h) * SEQ + s) * HD + d8] =
                *(const short8*)&T[mm * EPAD + hseg * 64 + d8];
        }
    } else if (mode == 3) {
        // K -> KPACK: stage [s][h*64+d], then store B-frags (1KB coalesced each)
        unsigned short* T = smem;
        __syncthreads();
#pragma unroll
        for (int mi = 0; mi < 4; ++mi)
#pragma unroll
            for (int ni = 0; ni < 4; ++ni)
#pragma unroll
                for (int r = 0; r < 4; ++r)
                    T[(wm * 64 + mi * 16 + quad * 4 + r) * EPAD + wn * 64 + ni * 16 + l16] =
                        f2b(acc[mi][ni][r] + bvv[ni]);
        __syncthreads();
#pragma unroll
        for (int it = 0; it < 8; ++it) {
            const int f = it * 256 + tid;
            const int ln = f & 63, fragid = f >> 6;
            const int h2 = fragid >> 4, j2 = (fragid >> 3) & 1;
            const int ni = (fragid >> 1) & 3, kk = fragid & 1;
            const int l16f = ln & 15, quadf = ln >> 4;
            const short8 v = *(const short8*)&T[(j2 * 64 + ni * 16 + l16f) * EPAD +
                                               h2 * 64 + kk * 32 + quadf * 8];
            const int bh = bb * NH + (n0 >> 6) + h2;
            const int jg = ((m0 & (SEQ - 1)) >> 6) + j2;
            *(short8*)&Cb[(((size_t)bh * 32 + jg) * 8 + ni * 2 + kk) * 512 + ln * 8] = v;
        }
    } else {
        // V -> VPACK: stage transposed [h*64+d][s], then store PV B-frags
        unsigned short* T = smem;
        __syncthreads();
#pragma unroll
        for (int mi = 0; mi < 4; ++mi)
#pragma unroll
            for (int ni = 0; ni < 4; ++ni) {
                ushort4v pk;
#pragma unroll
                for (int r = 0; r < 4; ++r) pk[r] = f2b(acc[mi][ni][r] + bvv[ni]);
                *(ushort4v*)&T[(wn * 64 + ni * 16 + l16) * EPAD + wm * 64 + mi * 16 + quad * 4] = pk;
            }
        __syncthreads();
#pragma unroll
        for (int it = 0; it < 8; ++it) {
            const int f = it * 256 + tid;
            const int ln = f & 63, fragid = f >> 6;
            const int h2 = fragid >> 4, j2 = (fragid >> 3) & 1;
            const int ni = (fragid >> 1) & 3, kk = fragid & 1;
            const int l16f = ln & 15, quadf = ln >> 4;
            const short8 v = *(const short8*)&T[(h2 * 64 + ni * 16 + l16f) * EPAD +
                                               j2 * 64 + kk * 32 + quadf * 8];
            const int bh = bb * NH + (n0 >> 6) + h2;
            const int jg = ((m0 & (SEQ - 1)) >> 6) + j2;
            *(short8*)&Cb[(((size_t)bh * 32 + jg) * 8 + ni * 2 + kk) * 512 + ln * 8] = v;
        }
    }
}

// ---------------- causal flash attention — BARRIER-FREE ----------------
// K/V pre-packed in MFMA B-frag order (KPACK/VPACK): each wave loads its
// B-operands directly from global (1KB coalesced b128 per frag). No K/V LDS,
// no __syncthreads anywhere; Ps and O-staging are wave-private LDS.
// grid (16 qtiles, 32 bh), qt reversed. Wave w owns 32 queries; its j-loop
// bound is exactly its causal range: jend = 2qt + (w>>1).
// Flat softmax (scores bounded): p = exp(s), masked -> 0; scale folded into Q.
__global__ __launch_bounds__(256) void attn_fwd(const unsigned short* __restrict__ Q,
                                                const unsigned short* __restrict__ KP,
                                                const unsigned short* __restrict__ VP,
                                                unsigned short* __restrict__ O) {
    __shared__ __attribute__((aligned(16))) unsigned short Os[4][32 * LPAD];  // per-wave

    const int qt = (gridDim.x - 1) - blockIdx.x;  // heavy blocks first
    const int bh = blockIdx.y;
    const int tid = threadIdx.x;
    const int w = tid >> 6, lane = tid & 63;
    const int quad = lane >> 4, l16 = lane & 15;

    const unsigned short* Qh  = Q  + (size_t)bh * SEQ * HD;
    const unsigned short* KPh = KP + (size_t)bh * 32 * 4096;
    const unsigned short* VPh = VP + (size_t)bh * 32 * 4096;
    const int q0 = qt * 128 + w * 32;

    // Q fragments (A-layout), pre-scaled by Hd^-0.5 = 0.125 (exact pow2 in bf16)
    short8 qf[2][2];
#pragma unroll
    for (int mi = 0; mi < 2; ++mi)
#pragma unroll
        for (int kk = 0; kk < 2; ++kk) {
            short8 t = *(const short8*)(Qh + (size_t)(q0 + mi * 16 + l16) * HD + kk * 32 + quad * 8);
            short8 o;
#pragma unroll
            for (int e = 0; e < 8; ++e)
                o[e] = (short)f2b(b2f((unsigned short)t[e]) * 0.125f);
            qf[mi][kk] = o;
        }

    floatx4 o_acc[2][4];
#pragma unroll
    for (int mi = 0; mi < 2; ++mi)
#pragma unroll
        for (int ni = 0; ni < 4; ++ni) o_acc[mi][ni] = (floatx4)0.0f;
    float l_i[2][4];
#pragma unroll
    for (int mi = 0; mi < 2; ++mi)
#pragma unroll
        for (int r = 0; r < 4; ++r) l_i[mi][r] = 0.0f;

    unsigned short* Ps = &Os[w][0];  // rows 0..15 during the loop (wave-private)
    const int jend = 2 * qt + (w >> 1);

    for (int j = 0; j <= jend; ++j) {
        const unsigned short* kb = KPh + (size_t)j * 4096 + lane * 8;
        const unsigned short* vb = VPh + (size_t)j * 4096 + lane * 8;
        short8 kf[4][2], vf[4][2];
#pragma unroll
        for (int ni = 0; ni < 4; ++ni)
#pragma unroll
            for (int kk = 0; kk < 2; ++kk) {
                kf[ni][kk] = *(const short8*)(kb + (ni * 2 + kk) * 512);
                vf[ni][kk] = *(const short8*)(vb + (ni * 2 + kk) * 512);
            }

        // S = Q K^T: 32 queries x 64 keys
        floatx4 s_acc[2][4];
#pragma unroll
        for (int mi = 0; mi < 2; ++mi)
#pragma unroll
            for (int ni = 0; ni < 4; ++ni) s_acc[mi][ni] = (floatx4)0.0f;
#pragma unroll
        for (int kk = 0; kk < 2; ++kk)
#pragma unroll
            for (int ni = 0; ni < 4; ++ni)
#pragma unroll
                for (int mi = 0; mi < 2; ++mi)
                    s_acc[mi][ni] = mfma_bf16(qf[mi][kk], kf[ni][kk], s_acc[mi][ni]);

        // flat softmax + PV per m-tile (all wave-private; no barriers)
#pragma unroll
        for (int mi = 0; mi < 2; ++mi) {
            float p[4][4], rs[4];
#pragma unroll
            for (int r = 0; r < 4; ++r) {
                const int q = q0 + mi * 16 + quad * 4 + r;
#pragma unroll
                for (int ni = 0; ni < 4; ++ni) {
                    const int key = j * 64 + ni * 16 + l16;
                    p[ni][r] = (key > q) ? 0.0f : __expf(s_acc[mi][ni][r]);
                }
                rs[r] = (p[0][r] + p[1][r]) + (p[2][r] + p[3][r]);
            }
#pragma unroll
            for (int off = 1; off < 16; off <<= 1)
#pragma unroll
                for (int r = 0; r < 4; ++r)
                    rs[r] += __shfl_xor(rs[r], off);
#pragma unroll
            for (int r = 0; r < 4; ++r) l_i[mi][r] += rs[r];

            // P: C-layout regs -> wave-private LDS -> A-layout frags
#pragma unroll
            for (int ni = 0; ni < 4; ++ni)
#pragma unroll
                for (int r = 0; r < 4; ++r)
                    Ps[(quad * 4 + r) * LPAD + ni * 16 + l16] = f2b(p[ni][r]);

#pragma unroll
            for (int kk = 0; kk < 2; ++kk) {
                const short8 pfrag = *(const short8*)&Ps[l16 * LPAD + kk * 32 + quad * 8];
#pragma unroll
                for (int ni = 0; ni < 4; ++ni)
                    o_acc[mi][ni] = mfma_bf16(pfrag, vf[ni][kk], o_acc[mi][ni]);
            }
        }
    }

    // O epilogue: normalize, stage per-wave [32 q][64 d], coalesced stores
    float inv[2][4];
#pragma unroll
    for (int mi = 0; mi < 2; ++mi)
#pragma unroll
        for (int r = 0; r < 4; ++r) inv[mi][r] = 1.0f / l_i[mi][r];
#pragma unroll
    for (int mi = 0; mi < 2; ++mi)
#pragma unroll
        for (int ni = 0; ni < 4; ++ni)
#pragma unroll
            for (int r = 0; r < 4; ++r)
                Os[w][(mi * 16 + quad * 4 + r) * LPAD + ni * 16 + l16] =
                    f2b(o_acc[mi][ni][r] * inv[mi][r]);
    const int bb = bh >> 4, h = bh & 15;
#pragma unroll
    for (int it = 0; it < 4; ++it) {
        const int row = it * 8 + (lane >> 3), d8 = (lane & 7) * 8;
        *(short8*)&O[(size_t)(bb * SEQ + q0 + row) * DIM + h * HD + d8] =
            *(const short8*)&Os[w][row * LPAD + d8];
    }
}

// ---------------- host launch ----------------
extern "C" void kernel_launch(void* const* d_in, const int* in_sizes, int n_in,
                              void* d_out, int out_size, void* d_ws, size_t ws_size,
                              hipStream_t stream) {
    // Reference dtypes are float32 — inputs and output are fp32.
    const float* X  = (const float*)d_in[0];
    const float* Wq = (const float*)d_in[1];
    const float* bq = (const float*)d_in[2];
    const float* Wk = (const float*)d_in[3];
    const float* bk = (const float*)d_in[4];
    const float* Wv = (const float*)d_in[5];
    const float* bv = (const float*)d_in[6];
    const float* Wo = (const float*)d_in[7];
    const float* bo = (const float*)d_in[8];

    unsigned short* ws = (unsigned short*)d_ws;
    const size_t WSZ = (size_t)DIM * DIM;    // 1M elems
    const size_t TSZ = (size_t)MTOT * DIM;   // 4M elems
    unsigned short* WqT = ws;                // 4 transposed weights (bf16), contiguous
    unsigned short* WoT = ws + 3 * WSZ;
    unsigned short* Qb  = ws + 4 * WSZ;      // Q [B,H,S,Hd]
    unsigned short* Kp  = Qb + TSZ;          // KPACK (B-frag order)
    unsigned short* Vp  = Kp + TSZ;          // VPACK (B-frag order)
    unsigned short* Ob  = Vp + TSZ;          // attn out [B,S,H*Hd] bf16
    // ws total: 4*2MB + 4*8MB = 40 MB

    // bf16 copy of X lives in d_out[0:8MB) — dead before the final GEMM
    // overwrites d_out with the fp32 result (16 MB).
    unsigned short* Xb = (unsigned short*)d_out;

    cvt_f32_bf16<<<dim3(TSZ / 1024), 256, 0, stream>>>(X, Xb);

    transpose_all<<<dim3(16, 16, 4), dim3(64, 4), 0, stream>>>(Wq, Wk, Wv, Wo, WqT);

    // fused QKV projections: Q -> [B,H,S,Hd], K -> KPACK, V -> VPACK
    gemm_fused<<<dim3(DIM / 128, MTOT / 128, 3), 256, 0, stream>>>(
        Xb, WqT, bq, bk, bv, (void*)Qb, 1);

    // barrier-free attention
    attn_fwd<<<dim3(SEQ / 128, 2 * NH), 256, 0, stream>>>(Qb, Kp, Vp, Ob);

    // output projection -> fp32 d_out
    gemm_fused<<<dim3(DIM / 128, MTOT / 128, 1), 256, 0, stream>>>(
        Ob, WoT, bo, bo, bo, d_out, 0);
}